// Round 15
// baseline (302.028 us; speedup 1.0000x reference)
//
#include <hip/hip_runtime.h>
#include <stdint.h>

#define Mdim 8192
#define Ndim 4096
#define Kdim 4096

#define BM 256
#define BN 256
#define BK 64
#define NT2 (Kdim / BK)   // 64 K-tiles

typedef float f32x4 __attribute__((ext_vector_type(4)));
typedef float f32x16 __attribute__((ext_vector_type(16)));
typedef __bf16 bf16x8 __attribute__((ext_vector_type(8)));
typedef unsigned short ushort_t;

#define FMAXC 3.3858093490333422e+38f  // FLT_MAX * (1 - 0.005)

__device__ __forceinline__ ushort_t f2bf(float f) {
    unsigned u = __float_as_uint(f);
    u += 0x7fffu + ((u >> 16) & 1u);   // round-to-nearest-even
    return (ushort_t)(u >> 16);
}

__device__ __forceinline__ void gload_lds16(const void* g, void* l) {
    __builtin_amdgcn_global_load_lds(
        (const __attribute__((address_space(1))) uint32_t*)g,
        (__attribute__((address_space(3))) uint32_t*)(uint32_t)(uintptr_t)l,
        16, 0, 0);
}

#define SGB(mask, n) __builtin_amdgcn_sched_group_barrier(mask, n, 0)

// ---------------------------------------------------------------------------
// Kernel 1: dequant + CSR outliers -> bf16 weight row (row-major, verified).
// ---------------------------------------------------------------------------
__global__ __launch_bounds__(128) void dequant_kernel(
        const int* __restrict__ qw, const float* __restrict__ lut,
        const int* __restrict__ rows, const int* __restrict__ cols,
        const float* __restrict__ vals, ushort_t* __restrict__ w16) {
    __shared__ float wrow[128 * 33];
    __shared__ float slut[16];
    const int o = blockIdx.x;
    const int t = threadIdx.x;

    if (t < 16) slut[t] = lut[o * 16 + t];
    __syncthreads();

    const int q0 = qw[0 * Ndim * 128 + o * 128 + t];
    const int q1 = qw[1 * Ndim * 128 + o * 128 + t];
    const int q2 = qw[2 * Ndim * 128 + o * 128 + t];
    const int q3 = qw[3 * Ndim * 128 + o * 128 + t];
    float* dst = &wrow[t * 33];
#pragma unroll
    for (int j = 0; j < 32; ++j) {
        int idx = (((q0 >> j) & 1) << 3) | (((q1 >> j) & 1) << 2) |
                  (((q2 >> j) & 1) << 1) | ((q3 >> j) & 1);
        dst[j] = slut[idx];
    }
    __syncthreads();

    const int beg = rows[o], end = rows[o + 1];
    for (int k = beg + t; k < end; k += 128) {
        int c = cols[k];
        atomicAdd(&wrow[c + (c >> 5)], vals[k]);
    }
    __syncthreads();

    __align__(16) ushort_t tmp[32];
#pragma unroll
    for (int j = 0; j < 32; ++j) tmp[j] = f2bf(dst[j]);
    uint4* dstg = (uint4*)(w16 + (size_t)o * Kdim + t * 32);
    const uint4* srcg = (const uint4*)tmp;
#pragma unroll
    for (int j = 0; j < 4; ++j) dstg[j] = srcg[j];
}

// ---------------------------------------------------------------------------
// Kernel 2: x f32 -> bf16. Unchanged (HBM-bound, ~30 us).
// ---------------------------------------------------------------------------
__global__ __launch_bounds__(256) void convx_kernel(
        const float* __restrict__ x, ushort_t* __restrict__ y) {
    size_t i = ((size_t)blockIdx.x * 256 + threadIdx.x) * 8;
    float4 a = *(const float4*)(x + i);
    float4 b = *(const float4*)(x + i + 4);
    __align__(16) ushort_t r[8] = {f2bf(a.x), f2bf(a.y), f2bf(a.z), f2bf(a.w),
                                   f2bf(b.x), f2bf(b.y), f2bf(b.z), f2bf(b.w)};
    *(uint4*)(y + i) = *(const uint4*)r;
}

// ---------------------------------------------------------------------------
// Kernel 3: bf16 GEMM = R9 structure (best, 233us) with the MFMA shape
// swapped to v_mfma_f32_32x32x16_bf16:
//   - matrix-pipe time/tile 2368 -> 2066 cyc (32x32 ubench 2495 vs 2176 TF)
//   - MFMA instruction count halves (64 -> 32 per wave-tile) -> issue relief
//   - LDS traffic identical (24 ds_read_b128 per wave per tile)
// Wave tile 128x64 = 4 mf x 2 nf fragments of 32x32; acc[4][2] f32x16.
// LDS 128 KiB: buf d at d*65536, A[256][64] @+0, B[256][64] @+32768;
// row stride 128 B, 8 slots/row, stored slot' = slot ^ (row&7) (R9 verified;
// 32x32 read pattern lands exactly 8 lanes/slot = b128 structural minimum).
// Read addr (mf, kstep ks, kg2 = lane>>5): row = wr*128+mf*32+(lane&31),
// slot = (ks*2+kg2) ^ (lane&7).  C/D layout (m74/m101): col = lane&31,
// row = (reg&3) + 8*(reg>>2) + 4*(lane>>5).
// Schedule per tile: stage 8 VMEM -> 24 ds_read -> 32 MFMA (setprio), SGB
// weave {VMEM 8}{DS 3, MFMA 4}x8, vmcnt(0) (issued a full tile ago), barrier.
// ---------------------------------------------------------------------------
__global__ __launch_bounds__(512, 2) void gemm_kernel(
        const ushort_t* __restrict__ A, const ushort_t* __restrict__ Bw,
        const float* __restrict__ bias, float* __restrict__ C) {
    __shared__ __align__(16) char lds[131072];

    // XCD swizzle, bn-fastest (R9): nwg=512 (%8==0)
    const int wgid = blockIdx.x;
    const int swz = (wgid & 7) * 64 + (wgid >> 3);
    const int bn = swz & 15, bm = swz >> 4;
    const int m0 = bm * BM, n0 = bn * BN;

    const int tid = threadIdx.x;
    const int lane = tid & 63, wid = tid >> 6;
    const int wr = wid >> 2, wc = wid & 3;       // 2M x 4N wave grid
    const int l31 = lane & 31, kg2 = lane >> 5;

    // ---- staging geometry (inverse-swizzled source, linear LDS dest) [R9]
    const int srow = tid >> 3;
    const int scol = (((tid & 7) ^ (srow & 7)) * 8);       // k elements
    const ushort_t* gA = A + (size_t)(m0 + srow) * Kdim + scol;
    const ushort_t* gB = Bw + (size_t)(n0 + srow) * Kdim + scol;

    // ---- ds_read swizzled lane offsets per k-step (row stride 128 B)
    int offK[4];
#pragma unroll
    for (int ks = 0; ks < 4; ++ks)
        offK[ks] = l31 * 128 + ((((ks << 1) | kg2) ^ (lane & 7)) << 4);

    f32x16 acc[4][2];
#pragma unroll
    for (int i = 0; i < 4; ++i)
#pragma unroll
        for (int j = 0; j < 2; ++j)
#pragma unroll
            for (int e = 0; e < 16; ++e) acc[i][j][e] = 0.f;

    auto stage = [&](int buf, int t1) {
        const ushort_t* sa = gA + (size_t)t1 * BK;
        const ushort_t* sb = gB + (size_t)t1 * BK;
        char* da = lds + buf * 65536 + tid * 16;
        char* db = da + 32768;
#pragma unroll
        for (int j = 0; j < 4; ++j) {
            gload_lds16(sa + (size_t)j * 64 * Kdim, da + j * 8192);
            gload_lds16(sb + (size_t)j * 64 * Kdim, db + j * 8192);
        }
    };
    auto readFrags = [&](bf16x8 (&FA)[4][4], bf16x8 (&FB)[2][4], const char* Ab,
                         const char* Bb) {
#pragma unroll
        for (int mf = 0; mf < 4; ++mf)
#pragma unroll
            for (int ks = 0; ks < 4; ++ks)
                FA[mf][ks] = *(const bf16x8*)(Ab + wr * 16384 + mf * 4096 + offK[ks]);
#pragma unroll
        for (int nf = 0; nf < 2; ++nf)
#pragma unroll
            for (int ks = 0; ks < 4; ++ks)
                FB[nf][ks] = *(const bf16x8*)(Bb + wc * 8192 + nf * 4096 + offK[ks]);
    };
    auto mfmaTile = [&](bf16x8 (&FA)[4][4], bf16x8 (&FB)[2][4]) {
        __builtin_amdgcn_s_setprio(1);
#pragma unroll
        for (int ks = 0; ks < 4; ++ks)
#pragma unroll
            for (int mf = 0; mf < 4; ++mf)
#pragma unroll
                for (int nf = 0; nf < 2; ++nf)
                    acc[mf][nf] = __builtin_amdgcn_mfma_f32_32x32x16_bf16(
                        FA[mf][ks], FB[nf][ks], acc[mf][nf], 0, 0, 0);
        __builtin_amdgcn_s_setprio(0);
    };

    // ---- prologue: stage tile 0 -> buf 0
    stage(0, 0);
    asm volatile("s_waitcnt vmcnt(0)");
    __builtin_amdgcn_sched_barrier(0);
    __builtin_amdgcn_s_barrier();

    // ===== main loop: tiles 0..NT2-2, one barrier per tile =====
#pragma unroll 1
    for (int t = 0; t < NT2 - 1; ++t) {
        const char* Ab = lds + (t & 1) * 65536;
        const char* Bb = Ab + 32768;

        bf16x8 FA[4][4], FB[2][4];
        readFrags(FA, FB, Ab, Bb);
        stage((t + 1) & 1, t + 1);
        mfmaTile(FA, FB);

        // SGB emission: 8 stage-VMEM first, then weave {3 DS, 4 MFMA} x 8
        SGB(0x30, 8);
#pragma unroll
        for (int i = 0; i < 8; ++i) { SGB(0x100, 3); SGB(0x8, 4); }

        asm volatile("s_waitcnt vmcnt(0)");    // stages issued a full tile ago
        __builtin_amdgcn_sched_barrier(0);
        __builtin_amdgcn_s_barrier();
    }

    // ===== tail: tile NT2-1 (no staging, no barrier) =====
    {
        const char* Ab = lds + ((NT2 - 1) & 1) * 65536;
        const char* Bb = Ab + 32768;
        bf16x8 FA[4][4], FB[2][4];
        readFrags(FA, FB, Ab, Bb);
        mfmaTile(FA, FB);
    }

    // ---- epilogue: 32x32 C/D layout: col = lane&31,
    //      row = (reg&3) + 8*(reg>>2) + 4*(lane>>5)
#pragma unroll
    for (int nf = 0; nf < 2; ++nf) {
        const int col = n0 + wc * 64 + nf * 32 + l31;
        const float bv = bias[col];
#pragma unroll
        for (int mf = 0; mf < 4; ++mf) {
            const int rowbase = m0 + wr * 128 + mf * 32 + 4 * kg2;
#pragma unroll
            for (int r = 0; r < 16; ++r) {
                const int row = rowbase + (r & 3) + 8 * (r >> 2);
                float v = acc[mf][nf][r] + bv;
                v = fminf(fmaxf(v, -FMAXC), FMAXC);
                C[(size_t)row * Ndim + col] = v;
            }
        }
    }
}

extern "C" void kernel_launch(void* const* d_in, const int* in_sizes, int n_in,
                              void* d_out, int out_size, void* d_ws, size_t ws_size,
                              hipStream_t stream) {
    const float* x    = (const float*)d_in[0];
    const int*   qw   = (const int*)d_in[1];
    const float* lut  = (const float*)d_in[2];
    const int*   rows = (const int*)d_in[3];
    const int*   cols = (const int*)d_in[4];
    const float* vals = (const float*)d_in[5];
    const float* bias = (const float*)d_in[6];
    float* out = (float*)d_out;

    ushort_t* x16 = (ushort_t*)d_ws;                       // 64 MiB
    ushort_t* w16 = x16 + (size_t)Mdim * Kdim;             // 32 MiB

    hipLaunchKernelGGL(dequant_kernel, dim3(Ndim), dim3(128), 0, stream,
                       qw, lut, rows, cols, vals, w16);
    hipLaunchKernelGGL(convx_kernel, dim3((Mdim * Kdim) / (256 * 8)), dim3(256), 0, stream,
                       x, x16);
    hipLaunchKernelGGL(gemm_kernel, dim3((Mdim / BM) * (Ndim / BN)), dim3(512), 0, stream,
                       x16, w16, bias, out);
}